// Round 1
// baseline (168.179 us; speedup 1.0000x reference)
//
#include <hip/hip_runtime.h>
#include <cstdint>

#define N_PIX 4096
#define CH    128
#define DD    64
#define NBATCH 8

typedef unsigned short u16;
typedef __attribute__((ext_vector_type(8))) short bf8_t;
typedef __attribute__((ext_vector_type(4))) float f4_t;

__device__ __forceinline__ u16 f2b(float f) {
  union { float f; uint32_t u; } v; v.f = f;
  uint32_t u = v.u;
  return (u16)((u + 0x7fffu + ((u >> 16) & 1u)) >> 16);
}

__device__ __forceinline__ f4_t mfma16(bf8_t a, bf8_t b, f4_t c) {
  return __builtin_amdgcn_mfma_f32_16x16x32_bf16(a, b, c, 0, 0, 0);
}

// ---------------------------------------------------------------------------
// Kernel 1: fused projections. theta_h[b][n][64], phi_h[b][n][64] (bf16, bias
// included), gt_h[b][64][n] (g transposed, bias included).
// GEMM: M=64 px, N'=192 (theta|phi|g), K=128 channels.
// ---------------------------------------------------------------------------
__global__ __launch_bounds__(256) void proj_kernel(
    const float* __restrict__ x,
    const float* __restrict__ tw, const float* __restrict__ tb,
    const float* __restrict__ pw, const float* __restrict__ pb,
    const float* __restrict__ gw, const float* __restrict__ gb,
    u16* __restrict__ theta_h, u16* __restrict__ phi_h, u16* __restrict__ gt_h) {
  __shared__ __align__(16) u16 xT[64][136];   // [px][c], pad 136 to dodge conflicts
  const int blk = blockIdx.x;
  const int b  = blk >> 6;
  const int n0 = (blk & 63) << 6;
  const int tid = threadIdx.x;

  // stage x tile [128 c][64 px] -> xT[px][c] as bf16
  #pragma unroll
  for (int i = 0; i < 8; ++i) {
    int idx = tid + i * 256;            // 0..2047, covers 128c x 16(px/4)
    int px = (idx & 15) * 4;
    int c  = idx >> 4;
    float4 v = *(const float4*)(x + ((size_t)b * CH + c) * N_PIX + n0 + px);
    xT[px + 0][c] = f2b(v.x);
    xT[px + 1][c] = f2b(v.y);
    xT[px + 2][c] = f2b(v.z);
    xT[px + 3][c] = f2b(v.w);
  }
  __syncthreads();

  const int lane = tid & 63;
  const int w    = tid >> 6;
  const int l4   = lane >> 4, l15 = lane & 15;

  // B-operand fragments: W'[o'][c], o' = 16*(3w+nt)+l15, 8 contiguous c per lane
  bf8_t bw[3][4];
  float bias[3];
  #pragma unroll
  for (int nt = 0; nt < 3; ++nt) {
    int op = 16 * (3 * w + nt) + l15;   // 0..191
    const float* wrow; float bv;
    if (op < 64)       { wrow = tw + op * CH;          bv = tb[op]; }
    else if (op < 128) { wrow = pw + (op - 64) * CH;   bv = pb[op - 64]; }
    else               { wrow = gw + (op - 128) * CH;  bv = gb[op - 128]; }
    bias[nt] = bv;
    #pragma unroll
    for (int ks = 0; ks < 4; ++ks) {
      const float* p = wrow + 32 * ks + l4 * 8;
      bf8_t v;
      #pragma unroll
      for (int j = 0; j < 8; ++j) v[j] = (short)f2b(p[j]);
      bw[nt][ks] = v;
    }
  }

  f4_t acc[4][3];
  #pragma unroll
  for (int mt = 0; mt < 4; ++mt)
    #pragma unroll
    for (int nt = 0; nt < 3; ++nt) acc[mt][nt] = (f4_t){0.f, 0.f, 0.f, 0.f};

  #pragma unroll
  for (int mt = 0; mt < 4; ++mt) {
    #pragma unroll
    for (int ks = 0; ks < 4; ++ks) {
      bf8_t a = *(const bf8_t*)&xT[l15 + 16 * mt][32 * ks + l4 * 8];
      #pragma unroll
      for (int nt = 0; nt < 3; ++nt)
        acc[mt][nt] = mfma16(a, bw[nt][ks], acc[mt][nt]);
    }
  }

  // C layout: row(px) = (l>>4)*4+r + 16mt, col(o') = l15 + 16*(3w+nt)
  #pragma unroll
  for (int nt = 0; nt < 3; ++nt) {
    int op = 16 * (3 * w + nt) + l15;
    #pragma unroll
    for (int mt = 0; mt < 4; ++mt) {
      #pragma unroll
      for (int r = 0; r < 4; ++r) {
        int q = n0 + 16 * mt + l4 * 4 + r;
        u16 h = f2b(acc[mt][nt][r] + bias[nt]);
        if (op < 64)       theta_h[((size_t)b * N_PIX + q) * DD + op] = h;
        else if (op < 128) phi_h[((size_t)b * N_PIX + q) * DD + (op - 64)] = h;
        else               gt_h[((size_t)b * DD + (op - 128)) * N_PIX + q] = h;
      }
    }
  }
}

// ---------------------------------------------------------------------------
// Kernel 2: flash attention. Block = 64 q-rows (4 waves x 16), KB=64 keys/iter.
// S = theta . phi^T (both [n][64] row-major), online softmax, y = P . g via
// gt[64][n]. P re-layout via LDS bounce. y_h[b][n][64] bf16 (pre-divided).
// ---------------------------------------------------------------------------
__global__ __launch_bounds__(256) void attn_kernel(
    const u16* __restrict__ theta_h, const u16* __restrict__ phi_h,
    const u16* __restrict__ gt_h, u16* __restrict__ y_h) {
  __shared__ __align__(16) u16 phi_lds[64][72];
  __shared__ __align__(16) u16 g_lds[64][72];
  __shared__ __align__(16) u16 P_lds[4][16][72];

  // XCD swizzle: keep each batch's phi/g working set on one XCD's L2.
  const int bid = blockIdx.x;              // 512 blocks, 512 % 8 == 0
  const int lb  = (bid & 7) * 64 + (bid >> 3);
  const int b   = lb >> 6;
  const int q0  = (lb & 63) << 6;
  const int tid = threadIdx.x;
  const int lane = tid & 63;
  const int w    = tid >> 6;
  const int l4   = lane >> 4, l15 = lane & 15;

  // theta A-fragments for this wave's 16 q rows (held in regs for all iters)
  const u16* trow = theta_h + ((size_t)b * N_PIX + q0 + 16 * w + l15) * DD + l4 * 8;
  bf8_t th0 = *(const bf8_t*)trow;
  bf8_t th1 = *(const bf8_t*)(trow + 32);

  f4_t yacc[4];
  #pragma unroll
  for (int ont = 0; ont < 4; ++ont) yacc[ont] = (f4_t){0.f, 0.f, 0.f, 0.f};
  float m_[4], l_[4];
  #pragma unroll
  for (int r = 0; r < 4; ++r) { m_[r] = -1e30f; l_[r] = 0.f; }

  const int srow = tid >> 2;          // 0..63
  const int scol = (tid & 3) * 16;    // 0,16,32,48 (bf16 cols)

  for (int kb = 0; kb < N_PIX / 64; ++kb) {
    // stage phi[kb*64 .. +64][64] and gt[0..64][kb*64 .. +64] into LDS
    {
      const uint4* src = (const uint4*)(phi_h + ((size_t)b * N_PIX + kb * 64 + srow) * DD + scol);
      uint4* dst = (uint4*)&phi_lds[srow][scol];
      dst[0] = src[0]; dst[1] = src[1];
      const uint4* src2 = (const uint4*)(gt_h + ((size_t)b * DD + srow) * N_PIX + kb * 64 + scol);
      uint4* dst2 = (uint4*)&g_lds[srow][scol];
      dst2[0] = src2[0]; dst2[1] = src2[1];
    }
    __syncthreads();

    // S tiles: this wave's 16 q x 64 m
    f4_t s[4];
    #pragma unroll
    for (int nt = 0; nt < 4; ++nt) {
      const u16* prow = &phi_lds[l15 + 16 * nt][l4 * 8];
      f4_t a = (f4_t){0.f, 0.f, 0.f, 0.f};
      a = mfma16(th0, *(const bf8_t*)prow, a);
      a = mfma16(th1, *(const bf8_t*)(prow + 32), a);
      s[nt] = a;
    }

    // online softmax: C layout row q=(l>>4)*4+r, col m=l15(+16nt)
    float scale[4];
    #pragma unroll
    for (int r = 0; r < 4; ++r) {
      float mx = fmaxf(fmaxf(s[0][r], s[1][r]), fmaxf(s[2][r], s[3][r]));
      mx = fmaxf(mx, __shfl_xor(mx, 1));
      mx = fmaxf(mx, __shfl_xor(mx, 2));
      mx = fmaxf(mx, __shfl_xor(mx, 4));
      mx = fmaxf(mx, __shfl_xor(mx, 8));
      float mn = fmaxf(m_[r], mx);
      float sc = __expf(m_[r] - mn);
      float sum = 0.f;
      #pragma unroll
      for (int nt = 0; nt < 4; ++nt) {
        float p = __expf(s[nt][r] - mn);
        s[nt][r] = p;
        sum += p;
      }
      sum += __shfl_xor(sum, 1);
      sum += __shfl_xor(sum, 2);
      sum += __shfl_xor(sum, 4);
      sum += __shfl_xor(sum, 8);
      l_[r] = l_[r] * sc + sum;
      m_[r] = mn;
      scale[r] = sc;
    }
    #pragma unroll
    for (int ont = 0; ont < 4; ++ont)
      #pragma unroll
      for (int r = 0; r < 4; ++r) yacc[ont][r] *= scale[r];

    // bounce P through LDS into A-fragment layout
    #pragma unroll
    for (int nt = 0; nt < 4; ++nt)
      #pragma unroll
      for (int r = 0; r < 4; ++r)
        P_lds[w][l4 * 4 + r][l15 + 16 * nt] = f2b(s[nt][r]);
    __syncthreads();

    // PV: y[q][o] += P[q][m] * g[m][o]
    #pragma unroll
    for (int ont = 0; ont < 4; ++ont) {
      const u16* pr = &P_lds[w][l15][l4 * 8];
      const u16* gr = &g_lds[l15 + 16 * ont][l4 * 8];
      yacc[ont] = mfma16(*(const bf8_t*)pr, *(const bf8_t*)gr, yacc[ont]);
      yacc[ont] = mfma16(*(const bf8_t*)(pr + 32), *(const bf8_t*)(gr + 32), yacc[ont]);
    }
    __syncthreads();
  }

  #pragma unroll
  for (int ont = 0; ont < 4; ++ont)
    #pragma unroll
    for (int r = 0; r < 4; ++r) {
      float v = yacc[ont][r] / l_[r];
      y_h[((size_t)b * N_PIX + q0 + 16 * w + l4 * 4 + r) * DD + l15 + 16 * ont] = f2b(v);
    }
}

// ---------------------------------------------------------------------------
// Kernel 3: out = out_w @ y + out_b + x. GEMM M=64 px, N=128 c, K=64.
// LDS transpose so fp32 stores (+residual) are coalesced along n.
// ---------------------------------------------------------------------------
__global__ __launch_bounds__(256) void outproj_kernel(
    const u16* __restrict__ y_h, const float* __restrict__ ow,
    const float* __restrict__ ob, const float* __restrict__ x,
    float* __restrict__ out) {
  __shared__ __align__(16) float ot[128][68];
  const int blk = blockIdx.x;
  const int b  = blk >> 6;
  const int n0 = (blk & 63) << 6;
  const int tid = threadIdx.x;
  const int lane = tid & 63;
  const int w    = tid >> 6;
  const int l4   = lane >> 4, l15 = lane & 15;

  bf8_t bw[2][2];
  float bias[2];
  #pragma unroll
  for (int nt = 0; nt < 2; ++nt) {
    int c = 16 * (2 * w + nt) + l15;
    bias[nt] = ob[c];
    #pragma unroll
    for (int ks = 0; ks < 2; ++ks) {
      const float* p = ow + c * DD + 32 * ks + l4 * 8;
      bf8_t v;
      #pragma unroll
      for (int j = 0; j < 8; ++j) v[j] = (short)f2b(p[j]);
      bw[nt][ks] = v;
    }
  }

  f4_t acc[4][2];
  #pragma unroll
  for (int mt = 0; mt < 4; ++mt)
    #pragma unroll
    for (int nt = 0; nt < 2; ++nt) acc[mt][nt] = (f4_t){0.f, 0.f, 0.f, 0.f};

  #pragma unroll
  for (int mt = 0; mt < 4; ++mt) {
    const u16* yr = y_h + ((size_t)b * N_PIX + n0 + 16 * mt + l15) * DD + l4 * 8;
    bf8_t a0 = *(const bf8_t*)yr;
    bf8_t a1 = *(const bf8_t*)(yr + 32);
    #pragma unroll
    for (int nt = 0; nt < 2; ++nt) {
      acc[mt][nt] = mfma16(a0, bw[nt][0], acc[mt][nt]);
      acc[mt][nt] = mfma16(a1, bw[nt][1], acc[mt][nt]);
    }
  }

  #pragma unroll
  for (int nt = 0; nt < 2; ++nt) {
    int c = 16 * (2 * w + nt) + l15;
    #pragma unroll
    for (int mt = 0; mt < 4; ++mt)
      #pragma unroll
      for (int r = 0; r < 4; ++r)
        ot[c][16 * mt + l4 * 4 + r] = acc[mt][nt][r] + bias[nt];
  }
  __syncthreads();

  #pragma unroll
  for (int i = 0; i < 8; ++i) {
    int idx = tid + i * 256;
    int px = (idx & 15) * 4;
    int c  = idx >> 4;
    size_t gi = ((size_t)b * CH + c) * N_PIX + n0 + px;
    float4 xv = *(const float4*)(x + gi);
    float4 o;
    o.x = ot[c][px + 0] + xv.x;
    o.y = ot[c][px + 1] + xv.y;
    o.z = ot[c][px + 2] + xv.z;
    o.w = ot[c][px + 3] + xv.w;
    *(float4*)(out + gi) = o;
  }
}

extern "C" void kernel_launch(void* const* d_in, const int* in_sizes, int n_in,
                              void* d_out, int out_size, void* d_ws, size_t ws_size,
                              hipStream_t stream) {
  const float* x  = (const float*)d_in[0];
  const float* tw = (const float*)d_in[1];
  const float* tb = (const float*)d_in[2];
  const float* pw = (const float*)d_in[3];
  const float* pb = (const float*)d_in[4];
  const float* gw = (const float*)d_in[5];
  const float* gb = (const float*)d_in[6];
  const float* ow = (const float*)d_in[7];
  const float* ob = (const float*)d_in[8];
  float* out = (float*)d_out;

  const size_t sz = (size_t)NBATCH * N_PIX * DD;   // elems per bf16 tensor
  u16* theta_h = (u16*)d_ws;
  u16* phi_h   = theta_h + sz;
  u16* gt_h    = phi_h + sz;
  u16* y_h     = gt_h + sz;

  proj_kernel<<<512, 256, 0, stream>>>(x, tw, tb, pw, pb, gw, gb, theta_h, phi_h, gt_h);
  attn_kernel<<<512, 256, 0, stream>>>(theta_h, phi_h, gt_h, y_h);
  outproj_kernel<<<512, 256, 0, stream>>>(y_h, ow, ob, x, out);
}

// Round 2
// 96.320 us; speedup vs baseline: 1.7460x; 1.7460x over previous
//
#include <hip/hip_runtime.h>
#include <cstdint>

#define N_PIX 4096
#define CH    128
#define DD    64
#define NBATCH 8
#define NT    32    // 4096 / 128 key-tiles

typedef unsigned short u16;
typedef __attribute__((ext_vector_type(8))) short bf8_t;
typedef __attribute__((ext_vector_type(4))) float f4_t;
typedef __attribute__((ext_vector_type(16))) float f16v;
typedef uint32_t u32x4 __attribute__((ext_vector_type(4)));

__device__ __forceinline__ u16 f2b(float f) {
  union { float f; uint32_t u; } v; v.f = f;
  uint32_t u = v.u;
  return (u16)((u + 0x7fffu + ((u >> 16) & 1u)) >> 16);
}
__device__ __forceinline__ float b2f(u16 h) {
  union { uint32_t u; float f; } v; v.u = ((uint32_t)h) << 16;
  return v.f;
}
__device__ __forceinline__ uint32_t pack2(float a, float b) {
  return (uint32_t)f2b(a) | ((uint32_t)f2b(b) << 16);
}

__device__ __forceinline__ f4_t mfma16(bf8_t a, bf8_t b, f4_t c) {
  return __builtin_amdgcn_mfma_f32_16x16x32_bf16(a, b, c, 0, 0, 0);
}
__device__ __forceinline__ f16v mfma32(bf8_t a, bf8_t b, f16v c) {
  return __builtin_amdgcn_mfma_f32_32x32x16_bf16(a, b, c, 0, 0, 0);
}
// v_permlane32_swap_b32 a, b:
//   a'[l<32]=a[l], a'[l>=32]=b[l-32];  b'[l<32]=a[l+32], b'[l>=32]=b[l]
__device__ __forceinline__ void pl32swap(uint32_t &a, uint32_t &b) {
  asm("v_permlane32_swap_b32 %0, %1" : "+v"(a), "+v"(b));
}

// ---------------------------------------------------------------------------
// Kernel 1: fused projections (unchanged from R1, validated).
// theta_h[b][n][64], phi_h[b][n][64], gt_h[b][64][n]  (bf16, bias included)
// ---------------------------------------------------------------------------
__global__ __launch_bounds__(256) void proj_kernel(
    const float* __restrict__ x,
    const float* __restrict__ tw, const float* __restrict__ tb,
    const float* __restrict__ pw, const float* __restrict__ pb,
    const float* __restrict__ gw, const float* __restrict__ gb,
    u16* __restrict__ theta_h, u16* __restrict__ phi_h, u16* __restrict__ gt_h) {
  __shared__ __align__(16) u16 xT[64][136];
  const int blk = blockIdx.x;
  const int b  = blk >> 6;
  const int n0 = (blk & 63) << 6;
  const int tid = threadIdx.x;

  #pragma unroll
  for (int i = 0; i < 8; ++i) {
    int idx = tid + i * 256;
    int px = (idx & 15) * 4;
    int c  = idx >> 4;
    float4 v = *(const float4*)(x + ((size_t)b * CH + c) * N_PIX + n0 + px);
    xT[px + 0][c] = f2b(v.x);
    xT[px + 1][c] = f2b(v.y);
    xT[px + 2][c] = f2b(v.z);
    xT[px + 3][c] = f2b(v.w);
  }
  __syncthreads();

  const int lane = tid & 63;
  const int w    = tid >> 6;
  const int l4   = lane >> 4, l15 = lane & 15;

  bf8_t bw[3][4];
  float bias[3];
  #pragma unroll
  for (int nt = 0; nt < 3; ++nt) {
    int op = 16 * (3 * w + nt) + l15;
    const float* wrow; float bv;
    if (op < 64)       { wrow = tw + op * CH;          bv = tb[op]; }
    else if (op < 128) { wrow = pw + (op - 64) * CH;   bv = pb[op - 64]; }
    else               { wrow = gw + (op - 128) * CH;  bv = gb[op - 128]; }
    bias[nt] = bv;
    #pragma unroll
    for (int ks = 0; ks < 4; ++ks) {
      const float* p = wrow + 32 * ks + l4 * 8;
      bf8_t v;
      #pragma unroll
      for (int j = 0; j < 8; ++j) v[j] = (short)f2b(p[j]);
      bw[nt][ks] = v;
    }
  }

  f4_t acc[4][3];
  #pragma unroll
  for (int mt = 0; mt < 4; ++mt)
    #pragma unroll
    for (int nt = 0; nt < 3; ++nt) acc[mt][nt] = (f4_t){0.f, 0.f, 0.f, 0.f};

  #pragma unroll
  for (int mt = 0; mt < 4; ++mt) {
    #pragma unroll
    for (int ks = 0; ks < 4; ++ks) {
      bf8_t a = *(const bf8_t*)&xT[l15 + 16 * mt][32 * ks + l4 * 8];
      #pragma unroll
      for (int nt = 0; nt < 3; ++nt)
        acc[mt][nt] = mfma16(a, bw[nt][ks], acc[mt][nt]);
    }
  }

  #pragma unroll
  for (int nt = 0; nt < 3; ++nt) {
    int op = 16 * (3 * w + nt) + l15;
    #pragma unroll
    for (int mt = 0; mt < 4; ++mt) {
      #pragma unroll
      for (int r = 0; r < 4; ++r) {
        int q = n0 + 16 * mt + l4 * 4 + r;
        u16 h = f2b(acc[mt][nt][r] + bias[nt]);
        if (op < 64)       theta_h[((size_t)b * N_PIX + q) * DD + op] = h;
        else if (op < 128) phi_h[((size_t)b * N_PIX + q) * DD + (op - 64)] = h;
        else               gt_h[((size_t)b * DD + (op - 128)) * N_PIX + q] = h;
      }
    }
  }
}

// ---------------------------------------------------------------------------
// Kernel 2: flash attention, 32x32 MFMA, swapped QK^T, in-register P path.
// Block: 512 threads = 8 waves = 2 q-groups (32 q each) x 4 m-slices.
// Tile: KB=128 keys; phi[128][64] + gt[64][128] double-buffered in LDS with
// 16B-chunk XOR swizzle (^ row&7). One barrier per tile. 4-way flash merge.
// ---------------------------------------------------------------------------
__global__ __launch_bounds__(512, 4) void attn_kernel(
    const u16* __restrict__ theta_h, const u16* __restrict__ phi_h,
    const u16* __restrict__ gt_h, u16* __restrict__ y_h) {
  // buf k (k=0,1): phi at u16 [k*16384, +8192), gt at [k*16384+8192, +8192)
  __shared__ __align__(16) u16 smem[32768];   // 64 KiB

  const int bid = blockIdx.x;                  // 512 blocks, 512 % 8 == 0
  const int lb  = (bid & 7) * 64 + (bid >> 3); // XCD swizzle: batch per XCD
  const int b   = lb >> 6;
  const int q0  = (lb & 63) << 6;
  const int tid = threadIdx.x;
  const int l   = tid & 63;
  const int w   = tid >> 6;
  const int qg  = w & 1;    // q-group (32 q)
  const int mh  = w >> 1;   // m-slice (32 of each 128-key tile)
  const int l31 = l & 31;
  const int hi  = l >> 5;

  // theta B-fragments: lane holds theta[q = q0+32qg+l31][k = 16kk+8hi .. +8)
  bf8_t th[4];
  {
    const u16* trow = theta_h + ((size_t)b * N_PIX + q0 + 32 * qg + l31) * DD;
    #pragma unroll
    for (int kk = 0; kk < 4; ++kk)
      th[kk] = *(const bf8_t*)(trow + 16 * kk + 8 * hi);
  }

  f16v yacc[2];
  #pragma unroll
  for (int ot = 0; ot < 2; ++ot)
    #pragma unroll
    for (int r = 0; r < 16; ++r) yacc[ot][r] = 0.f;
  float m_ = -1e30f, l_ = 0.f;

  // ---- staging addresses (per thread: 2 phi chunks + 2 gt chunks of 16B) --
  // phi tile rows r=0..127 (keys), 8 chunks/row; gt rows o=0..63, 16 chunks.
  const int pr  = tid >> 3, pc = tid & 7;          // phi id = tid, id+512
  const int go  = tid >> 4, gc = tid & 15;         // gt  id = tid, id+512
  const u16* phA = phi_h + ((size_t)b * N_PIX + pr) * DD + pc * 8;
  const u16* gtA = gt_h + ((size_t)b * DD + go) * N_PIX + gc * 8;
  const int pO0 = pr * 64 + ((pc ^ (pr & 7)) << 3);        // swizzled LDS off
  const int pO1 = pO0 + 4096;                               // row +64, same key
  const int gO0 = 8192 + go * 128 + ((gc ^ (go & 7)) << 3);
  const int gO1 = gO0 + 4096;                               // o +32, same key

  uint4 v0, v1, v2, v3;
  #define LOADS(kb_) do {                                              \
    v0 = *(const uint4*)(phA + (size_t)(kb_) * 8192);                  \
    v1 = *(const uint4*)(phA + (size_t)(kb_) * 8192 + 4096);           \
    v2 = *(const uint4*)(gtA + (size_t)(kb_) * 128);                   \
    v3 = *(const uint4*)(gtA + (size_t)(kb_) * 128 + 32 * (size_t)N_PIX); \
  } while (0)
  #define WRITES(buf_) do {                                            \
    u16* base_ = smem + (buf_) * 16384;                                \
    *(uint4*)(base_ + pO0) = v0;                                       \
    *(uint4*)(base_ + pO1) = v1;                                       \
    *(uint4*)(base_ + gO0) = v2;                                       \
    *(uint4*)(base_ + gO1) = v3;                                       \
  } while (0)

  LOADS(0); WRITES(0);
  __syncthreads();

  const int prow  = 32 * mh + l31;     // phi row this lane reads (A-frag)
  const int pbase = prow * 64;
  const int pkey  = prow & 7;

  for (int t = 0; t < NT; ++t) {
    const int cur = t & 1;
    if (t < NT - 1) LOADS(t + 1);
    const u16* pb = smem + cur * 16384;
    const u16* gb = pb + 8192;

    // ---- QK^T (swapped): ST[m][q] = phi . theta^T, 4 x mfma32 over K=64 ---
    f16v st;
    #pragma unroll
    for (int r = 0; r < 16; ++r) st[r] = 0.f;
    #pragma unroll
    for (int kk = 0; kk < 4; ++kk) {
      bf8_t a = *(const bf8_t*)(pb + pbase + (((2 * kk + hi) ^ pkey) << 3));
      st = mfma32(a, th[kk], st);
    }
    // lane holds ST[m_local = (r&3)+8*(r>>2)+4*hi][q = l31], m_local in 0..31

    // ---- online softmax (lane-local + one cross-half exchange) -----------
    float pmax = st[0];
    #pragma unroll
    for (int r = 1; r < 16; ++r) pmax = fmaxf(pmax, st[r]);
    pmax = fmaxf(pmax, __shfl_xor(pmax, 32));
    float mn = fmaxf(m_, pmax);
    float sc = __expf(m_ - mn);
    m_ = mn;
    float sum = 0.f;
    #pragma unroll
    for (int r = 0; r < 16; ++r) {
      float pe = __expf(st[r] - mn);
      st[r] = pe;
      sum += pe;
    }
    sum += __shfl_xor(sum, 32);
    l_ = l_ * sc + sum;
    #pragma unroll
    for (int ot = 0; ot < 2; ++ot)
      #pragma unroll
      for (int r = 0; r < 16; ++r) yacc[ot][r] *= sc;

    // ---- P -> PV B-fragments, fully in registers (pack + permlane swap) --
    uint32_t pk0 = pack2(st[0],  st[1]),  pk1 = pack2(st[2],  st[3]);
    uint32_t pk2 = pack2(st[4],  st[5]),  pk3 = pack2(st[6],  st[7]);
    uint32_t pk4 = pack2(st[8],  st[9]),  pk5 = pack2(st[10], st[11]);
    uint32_t pk6 = pack2(st[12], st[13]), pk7 = pack2(st[14], st[15]);
    uint32_t a0 = pk0, b0 = pk2; pl32swap(a0, b0);
    uint32_t a1 = pk1, b1 = pk3; pl32swap(a1, b1);
    uint32_t a2 = pk4, b2 = pk6; pl32swap(a2, b2);
    uint32_t a3 = pk5, b3 = pk7; pl32swap(a3, b3);
    bf8_t pf0 = __builtin_bit_cast(bf8_t, (u32x4){a0, a1, b0, b1}); // m 0..15
    bf8_t pf1 = __builtin_bit_cast(bf8_t, (u32x4){a2, a3, b2, b3}); // m 16..31

    // ---- PV: y^T[o][q] += gt[o][m] . P^T[m][q] ---------------------------
    #pragma unroll
    for (int ot = 0; ot < 2; ++ot) {
      int orow  = 32 * ot + l31;
      int obase = orow * 128;
      int okey  = orow & 7;
      bf8_t g0 = *(const bf8_t*)(gb + obase + ((((mh << 2) + hi)     ^ okey) << 3));
      yacc[ot] = mfma32(g0, pf0, yacc[ot]);
      bf8_t g1 = *(const bf8_t*)(gb + obase + ((((mh << 2) + 2 + hi) ^ okey) << 3));
      yacc[ot] = mfma32(g1, pf1, yacc[ot]);
    }

    if (t < NT - 1) WRITES(cur ^ 1);
    __syncthreads();
  }
  #undef LOADS
  #undef WRITES

  // ---- 4-way flash merge across m-slices (reuse smem) ---------------------
  // ypart (bf16): [qg][mh][o 0..63][q 0..31] at u16 idx 0 .. 16384
  // ml (f32):     [qg*4+mh][ m:q | l:32+q ]   at u16 idx 16384
  #pragma unroll
  for (int ot = 0; ot < 2; ++ot)
    #pragma unroll
    for (int r = 0; r < 16; ++r) {
      int o = 32 * ot + (r & 3) + 8 * (r >> 2) + 4 * hi;
      smem[(((qg * 4 + mh) * 64 + o) << 5) + l31] = f2b(yacc[ot][r]);
    }
  float* ml = (float*)(smem + 16384);
  if (hi == 0) {
    ml[(qg * 4 + mh) * 64 + l31]      = m_;
    ml[(qg * 4 + mh) * 64 + 32 + l31] = l_;
  }
  __syncthreads();

  {
    const int qg2 = tid >> 8;
    const int rem = tid & 255;
    const int qq  = rem & 31;
    const int og  = rem >> 5;   // 8 o-octets
    float mi[4], li[4];
    #pragma unroll
    for (int i = 0; i < 4; ++i) {
      mi[i] = ml[(qg2 * 4 + i) * 64 + qq];
      li[i] = ml[(qg2 * 4 + i) * 64 + 32 + qq];
    }
    float M = fmaxf(fmaxf(mi[0], mi[1]), fmaxf(mi[2], mi[3]));
    float e[4], L = 0.f;
    #pragma unroll
    for (int i = 0; i < 4; ++i) { e[i] = __expf(mi[i] - M); L += li[i] * e[i]; }
    float invL = 1.0f / L;
    float acc[8];
    #pragma unroll
    for (int oo = 0; oo < 8; ++oo) {
      int o = og * 8 + oo;
      float a = 0.f;
      #pragma unroll
      for (int i = 0; i < 4; ++i)
        a += b2f(smem[(((qg2 * 4 + i) * 64 + o) << 5) + qq]) * e[i];
      acc[oo] = a * invL;
    }
    uint4 ov;
    ov.x = pack2(acc[0], acc[1]);
    ov.y = pack2(acc[2], acc[3]);
    ov.z = pack2(acc[4], acc[5]);
    ov.w = pack2(acc[6], acc[7]);
    *(uint4*)(y_h + ((size_t)b * N_PIX + q0 + 32 * qg2 + qq) * DD + og * 8) = ov;
  }
}

// ---------------------------------------------------------------------------
// Kernel 3: out = out_w @ y + out_b + x (unchanged from R1, validated).
// ---------------------------------------------------------------------------
__global__ __launch_bounds__(256) void outproj_kernel(
    const u16* __restrict__ y_h, const float* __restrict__ ow,
    const float* __restrict__ ob, const float* __restrict__ x,
    float* __restrict__ out) {
  __shared__ __align__(16) float ot[128][68];
  const int blk = blockIdx.x;
  const int b  = blk >> 6;
  const int n0 = (blk & 63) << 6;
  const int tid = threadIdx.x;
  const int lane = tid & 63;
  const int w    = tid >> 6;
  const int l4   = lane >> 4, l15 = lane & 15;

  bf8_t bw[2][2];
  float bias[2];
  #pragma unroll
  for (int nt = 0; nt < 2; ++nt) {
    int c = 16 * (2 * w + nt) + l15;
    bias[nt] = ob[c];
    #pragma unroll
    for (int ks = 0; ks < 2; ++ks) {
      const float* p = ow + c * DD + 32 * ks + l4 * 8;
      bf8_t v;
      #pragma unroll
      for (int j = 0; j < 8; ++j) v[j] = (short)f2b(p[j]);
      bw[nt][ks] = v;
    }
  }

  f4_t acc[4][2];
  #pragma unroll
  for (int mt = 0; mt < 4; ++mt)
    #pragma unroll
    for (int nt = 0; nt < 2; ++nt) acc[mt][nt] = (f4_t){0.f, 0.f, 0.f, 0.f};

  #pragma unroll
  for (int mt = 0; mt < 4; ++mt) {
    const u16* yr = y_h + ((size_t)b * N_PIX + n0 + 16 * mt + l15) * DD + l4 * 8;
    bf8_t a0 = *(const bf8_t*)yr;
    bf8_t a1 = *(const bf8_t*)(yr + 32);
    #pragma unroll
    for (int nt = 0; nt < 2; ++nt) {
      acc[mt][nt] = mfma16(a0, bw[nt][0], acc[mt][nt]);
      acc[mt][nt] = mfma16(a1, bw[nt][1], acc[mt][nt]);
    }
  }

  #pragma unroll
  for (int nt = 0; nt < 2; ++nt) {
    int c = 16 * (2 * w + nt) + l15;
    #pragma unroll
    for (int mt = 0; mt < 4; ++mt)
      #pragma unroll
      for (int r = 0; r < 4; ++r)
        ot[c][16 * mt + l4 * 4 + r] = acc[mt][nt][r] + bias[nt];
  }
  __syncthreads();

  #pragma unroll
  for (int i = 0; i < 8; ++i) {
    int idx = tid + i * 256;
    int px = (idx & 15) * 4;
    int c  = idx >> 4;
    size_t gi = ((size_t)b * CH + c) * N_PIX + n0 + px;
    float4 xv = *(const float4*)(x + gi);
    float4 o;
    o.x = ot[c][px + 0] + xv.x;
    o.y = ot[c][px + 1] + xv.y;
    o.z = ot[c][px + 2] + xv.z;
    o.w = ot[c][px + 3] + xv.w;
    *(float4*)(out + gi) = o;
  }
}

extern "C" void kernel_launch(void* const* d_in, const int* in_sizes, int n_in,
                              void* d_out, int out_size, void* d_ws, size_t ws_size,
                              hipStream_t stream) {
  const float* x  = (const float*)d_in[0];
  const float* tw = (const float*)d_in[1];
  const float* tb = (const float*)d_in[2];
  const float* pw = (const float*)d_in[3];
  const float* pb = (const float*)d_in[4];
  const float* gw = (const float*)d_in[5];
  const float* gb = (const float*)d_in[6];
  const float* ow = (const float*)d_in[7];
  const float* ob = (const float*)d_in[8];
  float* out = (float*)d_out;

  const size_t sz = (size_t)NBATCH * N_PIX * DD;
  u16* theta_h = (u16*)d_ws;
  u16* phi_h   = theta_h + sz;
  u16* gt_h    = phi_h + sz;
  u16* y_h     = gt_h + sz;

  proj_kernel<<<512, 256, 0, stream>>>(x, tw, tb, pw, pb, gw, gb, theta_h, phi_h, gt_h);
  attn_kernel<<<512, 512, 0, stream>>>(theta_h, phi_h, gt_h, y_h);
  outproj_kernel<<<512, 256, 0, stream>>>(y_h, ow, ob, x, out);
}